// Round 13
// baseline (65.040 us; speedup 1.0000x reference)
//
#include <hip/hip_runtime.h>

#define D 256

typedef __attribute__((ext_vector_type(8))) _Float16 f16x8;
typedef __attribute__((ext_vector_type(8))) short    s16x8;
typedef __attribute__((ext_vector_type(4))) float    f4_t;

// ---- conv: numpy-pairwise rowsq for x and cb; fp16 panel-permute for cb only
// blocks [0,nx): x -> x2 only ; blocks [nx, nx+K/16): cb -> Eh + e2
__global__ __launch_bounds__(256) void conv_all(
    const float* __restrict__ x, const float* __restrict__ cb,
    short* __restrict__ eh, float* __restrict__ x2, float* __restrict__ e2,
    int nx) {
    __shared__ float tile[16 * 264];
    const int t = threadIdx.x;
    const int bid = blockIdx.x;
    const bool isX = bid < nx;
    const float* in = isX ? x : cb;
    float* sq = isX ? x2 : e2;
    const int p = isX ? bid : bid - nx;
    const float* src = in + (size_t)p * 16 * 256;
#pragma unroll
    for (int it = 0; it < 4; ++it) {
        int idx = it * 256 + t;
        int row = idx >> 6, c4 = idx & 63;
        float4 v = *(const float4*)(src + row * 256 + c4 * 4);
        *(float4*)(tile + row * 264 + c4 * 4) = v;
    }
    __syncthreads();
    {   // rowsq: 16 threads/row, numpy pairwise order (8 strided accs + tree)
        int row = t >> 4, lane = t & 15;
        int b = lane >> 3, j = lane & 7;
        const float* q = tile + row * 264 + b * 128 + j;
        float r = 0.f;
        {
#pragma clang fp contract(off)
            for (int i = 0; i < 16; ++i) { float v = q[8 * i]; float s2 = v * v; r = r + s2; }
        }
        r += __shfl_xor(r, 1); r += __shfl_xor(r, 2);
        r += __shfl_xor(r, 4); r += __shfl_xor(r, 8);
        if (lane == 0) sq[p * 16 + row] = r;
    }
    if (!isX) {                                  // cb only: permute + fp16 (RTE)
#pragma unroll
        for (int jj = 0; jj < 2; ++jj) {
            int sl = jj * 256 + t;
            int s = sl >> 6, chunk = (sl >> 4) & 3, rr = sl & 15;
            const float* q = tile + rr * 264 + s * 32 + chunk * 8;
            s16x8 h8;
#pragma unroll
            for (int e = 0; e < 8; ++e) {
                _Float16 hv = (_Float16)q[e];
                h8[e] = (short)__builtin_bit_cast(unsigned short, hv);
            }
            *(s16x8*)(eh + (size_t)p * 4096 + (size_t)sl * 8) = h8;
        }
    }
}

// ---- main: 128 rows x 256 codes (quarter); R11-proven 2-barrier schedule ---
// A read DIRECTLY from fp32 x (converted in-reg, RTE == old conv path); the
// 4 quarter-blocks re-read each 128-row slab, absorbed by L2/L3 (R12 showed
// re-reads are free). 4 waves x 32 rows, A in regs, 4 LDS bufs (33KB -> 4
// blocks/CU). Iteration s: STAGE(2s+2),(2s+3); vmcnt(4); [barrier; read
// panels 2s,2s+1; MFMA; fold; barrier]. A-loads are all consumed before the
// prologue __syncthreads (vmcnt 0 there) so the in-loop vmcnt(4) counts only
// global_load_lds: after this iter's STAGE outstanding=8, vmcnt(4) drains
// exactly panels 2s,2s+1. WAR: STAGE(2s+2) writes buf (2s-2)&3, read in
// superphase s-1, completed before s-1's END barrier (R8/R11-validated).
__global__ __launch_bounds__(256, 4) void vq_gemm(
    const float* __restrict__ x, const short* __restrict__ Eh,
    const float* __restrict__ e2, int* __restrict__ cand) {
    __shared__ short Bs[4 * 4096];              // 4 panel bufs x 8KB = 32KB
    __shared__ float e2s[256];
    const int tid = threadIdx.x;
    const int l = tid & 63;
    const int w = tid >> 6;
    const int rb = blockIdx.x & 255;            // R11 mapping (swizzle reverted)
    const int q  = blockIdx.x >> 8;             // code quarter
    const int R0 = rb * 128;
    const int pcBase = q * 16;

#define STAGE(pp) do {                                                        \
    const short* g_ = Eh + (size_t)(pcBase + (pp)) * 4096 + w * 512 + l * 8;  \
    short* d_ = (short*)Bs + ((pp) & 3) * 4096 + w * 512;                     \
    __builtin_amdgcn_global_load_lds(                                         \
        (const __attribute__((address_space(1))) void*)g_,                    \
        (__attribute__((address_space(3))) void*)d_, 16, 0, 0);               \
    __builtin_amdgcn_global_load_lds(                                         \
        (const __attribute__((address_space(1))) void*)(g_ + 2048),           \
        (__attribute__((address_space(3))) void*)(d_ + 2048), 16, 0, 0);      \
} while (0)

    // A: wave's 32 rows x 256 k, direct fp32 load + fp16 convert (one-time)
    f16x8 aa[2][8];
    {
        const int rr_ = l & 15, ch_ = l >> 4;
#pragma unroll
        for (int m = 0; m < 2; ++m)
#pragma unroll
            for (int s = 0; s < 8; ++s) {
                const float* sp = x + (size_t)(R0 + w * 32 + m * 16 + rr_) * D
                                + s * 32 + ch_ * 8;
                float4 v0 = *(const float4*)sp;
                float4 v1 = *(const float4*)(sp + 4);
                f16x8 h;
                h[0] = (_Float16)v0.x; h[1] = (_Float16)v0.y;
                h[2] = (_Float16)v0.z; h[3] = (_Float16)v0.w;
                h[4] = (_Float16)v1.x; h[5] = (_Float16)v1.y;
                h[6] = (_Float16)v1.z; h[7] = (_Float16)v1.w;
                aa[m][s] = h;
            }
    }

    e2s[tid] = 0.5f * e2[q * 256 + tid] + 256.0f;

    STAGE(0); STAGE(1);                         // panels 0,1
    __syncthreads();                            // full drain + e2s visibility

    unsigned int k1[2][4], k2[2][4];
#pragma unroll
    for (int m = 0; m < 2; ++m)
#pragma unroll
        for (int r = 0; r < 4; ++r) { k1[m][r] = 0xFFFFFFFFu; k2[m][r] = 0xFFFFFFFFu; }

#define SPBODY(S)                                                             \
    __builtin_amdgcn_s_barrier();                                             \
    asm volatile("" ::: "memory");                                            \
    _Pragma("unroll")                                                         \
    for (int hp = 0; hp < 2; ++hp) {                                          \
        const int p = 2 * (S) + hp;                                           \
        const short* bp = (const short*)Bs + (p & 3) * 4096;                  \
        f4_t acc[2][2];                                                       \
        _Pragma("unroll")                                                     \
        for (int m = 0; m < 2; ++m) {                                         \
            f4_t z = {0.f,0.f,0.f,0.f}; acc[m][0] = z; acc[m][1] = z;         \
        }                                                                     \
        __builtin_amdgcn_s_setprio(1);                                        \
        {                                                                     \
            f16x8 bb[4];                                                      \
            _Pragma("unroll")                                                 \
            for (int k = 0; k < 4; ++k)                                       \
                bb[k] = *(const f16x8*)(bp + k * 512 + l * 8);                \
            _Pragma("unroll")                                                 \
            for (int k = 0; k < 4; ++k)                                       \
                _Pragma("unroll")                                             \
                for (int m = 0; m < 2; ++m)                                   \
                    acc[m][0] = __builtin_amdgcn_mfma_f32_16x16x32_f16(       \
                        aa[m][k], bb[k], acc[m][0], 0, 0, 0);                 \
        }                                                                     \
        {                                                                     \
            f16x8 bb[4];                                                      \
            _Pragma("unroll")                                                 \
            for (int k = 0; k < 4; ++k)                                       \
                bb[k] = *(const f16x8*)(bp + (k + 4) * 512 + l * 8);          \
            _Pragma("unroll")                                                 \
            for (int k = 0; k < 4; ++k)                                       \
                _Pragma("unroll")                                             \
                for (int m = 0; m < 2; ++m)                                   \
                    acc[m][1] = __builtin_amdgcn_mfma_f32_16x16x32_f16(       \
                        aa[m][k + 4], bb[k], acc[m][1], 0, 0, 0);             \
        }                                                                     \
        __builtin_amdgcn_s_setprio(0);                                        \
        const unsigned int code = (unsigned int)(q * 256 + p * 16 + (l & 15));\
        const float e2b = e2s[p * 16 + (l & 15)];                             \
        _Pragma("unroll")                                                     \
        for (int m = 0; m < 2; ++m)                                           \
            _Pragma("unroll")                                                 \
            for (int r = 0; r < 4; ++r) {                                     \
                float v = e2b - (acc[m][0][r] + acc[m][1][r]);                \
                unsigned int u = __builtin_bit_cast(unsigned int, v);         \
                unsigned int key = (u & 0xFFFFFC00u) | code;  /* v>233>0 */   \
                unsigned int mx = k1[m][r] > key ? k1[m][r] : key;            \
                k1[m][r] = k1[m][r] < key ? k1[m][r] : key;                   \
                k2[m][r] = k2[m][r] < mx ? k2[m][r] : mx;                     \
            }                                                                 \
    }                                                                         \
    __builtin_amdgcn_s_barrier();                                             \
    asm volatile("" ::: "memory");

#pragma unroll 1
    for (int s = 0; s < 7; ++s) {               // stage 1 superphase ahead
        STAGE(2 * s + 2); STAGE(2 * s + 3);
        asm volatile("s_waitcnt vmcnt(4)" ::: "memory");
        SPBODY(s)
    }
    {                                           // tail: nothing left to stage
        asm volatile("s_waitcnt vmcnt(0)" ::: "memory");
        SPBODY(7)
    }

    // top-2 reduce across the 16 lanes sharing each row; write candidates
    {
        int q4 = l >> 4;
#pragma unroll
        for (int m = 0; m < 2; ++m)
#pragma unroll
            for (int r = 0; r < 4; ++r) {
                unsigned int a = k1[m][r], b = k2[m][r];
#pragma unroll
                for (int msk = 1; msk < 16; msk <<= 1) {
                    unsigned int oa = __shfl_xor(a, msk);
                    unsigned int ob = __shfl_xor(b, msk);
                    unsigned int hi_ = a > oa ? a : oa;
                    a = a < oa ? a : oa;
                    b = b < ob ? b : ob;
                    b = b < hi_ ? b : hi_;
                }
                if ((l & 15) == 0) {
                    int row = R0 + w * 32 + m * 16 + q4 * 4 + r;
                    int2 o; o.x = (int)(a & 1023u); o.y = (int)(b & 1023u);
                    *(int2*)(cand + (size_t)row * 8 + q * 2) = o;
                }
            }
    }
#undef SPBODY
#undef STAGE
}

// ---- exact fp32 recheck of 8 candidates (ref formula + tie-break) + gather --
__global__ __launch_bounds__(256) void vq_decide(const float* __restrict__ x,
    const float* __restrict__ cb, const int* __restrict__ cand,
    const float* __restrict__ x2, const float* __restrict__ e2,
    float* __restrict__ outq, float* __restrict__ outi) {
    const int w = threadIdx.x >> 6, l = threadIdx.x & 63;
    const int row = blockIdx.x * 4 + w;
    const int o = l >> 3, j = l & 7;
    const int c = cand[(size_t)row * 8 + o];
    const float4* xr = (const float4*)(x + (size_t)row * D);
    const float4* er = (const float4*)(cb + (size_t)c * D);
    float xe = 0.f;
#pragma unroll
    for (int i = 0; i < 8; ++i) {
        float4 xv = xr[i * 8 + j], ev = er[i * 8 + j];
        xe = fmaf(xv.x, ev.x, xe); xe = fmaf(xv.y, ev.y, xe);
        xe = fmaf(xv.z, ev.z, xe); xe = fmaf(xv.w, ev.w, xe);
    }
    xe += __shfl_xor(xe, 1); xe += __shfl_xor(xe, 2); xe += __shfl_xor(xe, 4);
    float s0 = x2[row] + e2[c];                 // ref order: (x2 + e2) first
    float dist = s0 - 2.f * xe;                 // then - 2*xe
    float best = 3.4e38f; int bi = 0x7fffffff;
#pragma unroll
    for (int oq = 0; oq < 8; ++oq) {
        float dd = __shfl(dist, oq * 8);
        int   ii = __shfl(c,    oq * 8);
        if (dd < best || (dd == best && ii < bi)) { best = dd; bi = ii; }
    }
    float4 v = ((const float4*)(cb + (size_t)bi * D))[l];
    ((float4*)(outq + (size_t)row * D))[l] = v;
    if (l == 0) outi[row] = (float)bi;
}

extern "C" void kernel_launch(void* const* d_in, const int* in_sizes, int n_in,
                              void* d_out, int out_size, void* d_ws, size_t ws_size,
                              hipStream_t stream) {
    const float* x  = (const float*)d_in[0];
    const float* cb = (const float*)d_in[1];
    const int N  = in_sizes[0] / D;   // 32768
    const int Kc = in_sizes[1] / D;   // 1024

    float* outq = (float*)d_out;
    float* outi = outq + (size_t)N * D;

    // Workspace: Eh 512KB + e2 4KB + x2 128KB + cand 1MB ~= 1.7MB.
    // (ws_size is ~268MB in this harness -- fills observed in rocprof.)
    short* Eh  = (short*)d_ws;
    float* e2  = (float*)(Eh + (size_t)Kc * D);
    float* x2  = e2 + Kc;
    int*  cand = (int*)(x2 + N);

    conv_all<<<N / 16 + Kc / 16, 256, 0, stream>>>(x, cb, Eh, x2, e2, N / 16);
    vq_gemm<<<(N / 128) * 4, 256, 0, stream>>>(x, Eh, e2, cand);
    vq_decide<<<N / 4, 256, 0, stream>>>(x, cb, cand, x2, e2, outq, outi);
}

// Round 14
// 58.693 us; speedup vs baseline: 1.1081x; 1.1081x over previous
//
#include <hip/hip_runtime.h>

#define D 256

typedef __attribute__((ext_vector_type(8))) _Float16 f16x8;
typedef __attribute__((ext_vector_type(8))) short    s16x8;
typedef __attribute__((ext_vector_type(4))) float    f4_t;

// ---- merged conv: fp32 -> fp16 panel-permute + numpy-pairwise rowsq --------
// blocks [0,nx): x -> xh,x2 ; blocks [nx, nx+K/16): cb -> eh,e2
__global__ __launch_bounds__(256) void conv_all(
    const float* __restrict__ x, short* __restrict__ xh, float* __restrict__ x2,
    const float* __restrict__ cb, short* __restrict__ eh, float* __restrict__ e2,
    int nx) {
    __shared__ float tile[16 * 264];
    const int t = threadIdx.x;
    const int bid = blockIdx.x;
    const float* in; short* out; float* sq; int p;
    if (bid < nx) { in = x;  out = xh; sq = x2; p = bid; }
    else          { in = cb; out = eh; sq = e2; p = bid - nx; }
    const float* src = in + (size_t)p * 16 * 256;
#pragma unroll
    for (int it = 0; it < 4; ++it) {
        int idx = it * 256 + t;
        int row = idx >> 6, c4 = idx & 63;
        float4 v = *(const float4*)(src + row * 256 + c4 * 4);
        *(float4*)(tile + row * 264 + c4 * 4) = v;
    }
    __syncthreads();
    {   // rowsq: 16 threads/row, numpy pairwise order
        int row = t >> 4, lane = t & 15;
        int b = lane >> 3, j = lane & 7;
        const float* q = tile + row * 264 + b * 128 + j;
        float r = 0.f;
        {
#pragma clang fp contract(off)
            for (int i = 0; i < 16; ++i) { float v = q[8 * i]; float s2 = v * v; r = r + s2; }
        }
        r += __shfl_xor(r, 1); r += __shfl_xor(r, 2);
        r += __shfl_xor(r, 4); r += __shfl_xor(r, 8);
        if (lane == 0) sq[p * 16 + row] = r;
    }
#pragma unroll
    for (int jj = 0; jj < 2; ++jj) {
        int sl = jj * 256 + t;
        int s = sl >> 6, chunk = (sl >> 4) & 3, rr = sl & 15;
        const float* q = tile + rr * 264 + s * 32 + chunk * 8;
        s16x8 h8;
#pragma unroll
        for (int e = 0; e < 8; ++e) {
            _Float16 hv = (_Float16)q[e];
            h8[e] = (short)__builtin_bit_cast(unsigned short, hv);
        }
        *(s16x8*)(out + (size_t)p * 4096 + (size_t)sl * 8) = h8;
    }
}

// ---- main: 256 rows x 256 codes (quarter); 64 rows/WAVE (2x LDS reuse) -----
// 4 waves x 64 rows, A in registers (32 frags, 128 VGPR); 4 LDS bufs (33KB ->
// 2 blocks/CU, 2 waves/SIMD, VGPR budget 256 via launch_bounds(256,2)).
// Each 8KB panel read now feeds 32 MFMAs (was 16) -> LDS pipe (the prior
// binding term, ~105 B/cy needed vs 85 measured) drops below the MFMA floor.
// Sync skeleton identical to R11 (validated): iteration s: STAGE(2s+2),(2s+3);
// vmcnt(4); [barrier; read panels 2s,2s+1; MFMA; fold; barrier]. Residency:
// panels 2s,2s+1 staged at s-1; after this iter's STAGE outstanding=8,
// vmcnt(4) drains exactly them; entry barrier => all waves' chunks resident.
// WAR: STAGE(2s+2) writes buf (2s-2)&3, read in superphase s-1, completed
// before s-1's END barrier.
__global__ __launch_bounds__(256, 2) void vq_gemm(
    const short* __restrict__ Xh, const short* __restrict__ Eh,
    const float* __restrict__ e2, int* __restrict__ cand) {
    __shared__ short Bs[4 * 4096];              // 4 panel bufs x 8KB = 32KB
    __shared__ float e2s[256];
    const int tid = threadIdx.x;
    const int l = tid & 63;
    const int w = tid >> 6;
    const int rb = blockIdx.x & 127;            // 128 row-blocks of 256 rows
    const int q  = blockIdx.x >> 7;             // code quarter
    const int R0 = rb * 256;
    const int pcBase = q * 16;

#define STAGE(pp) do {                                                        \
    const short* g_ = Eh + (size_t)(pcBase + (pp)) * 4096 + w * 512 + l * 8;  \
    short* d_ = (short*)Bs + ((pp) & 3) * 4096 + w * 512;                     \
    __builtin_amdgcn_global_load_lds(                                         \
        (const __attribute__((address_space(1))) void*)g_,                    \
        (__attribute__((address_space(3))) void*)d_, 16, 0, 0);               \
    __builtin_amdgcn_global_load_lds(                                         \
        (const __attribute__((address_space(1))) void*)(g_ + 2048),           \
        (__attribute__((address_space(3))) void*)(d_ + 2048), 16, 0, 0);      \
} while (0)

    // A: wave's 64 rows x 256 k, 32 fragments in registers (loaded once)
    f16x8 aa[4][8];
#pragma unroll
    for (int m = 0; m < 4; ++m)
#pragma unroll
        for (int s = 0; s < 8; ++s)
            aa[m][s] = *(const f16x8*)(Xh +
                (size_t)((R0 >> 4) + w * 4 + m) * 4096 + s * 512 + l * 8);

    e2s[tid] = 0.5f * e2[q * 256 + tid] + 256.0f;

    STAGE(0); STAGE(1);                         // panels 0,1
    __syncthreads();                            // full drain + e2s visibility

    unsigned int k1[4][4], k2[4][4];
#pragma unroll
    for (int m = 0; m < 4; ++m)
#pragma unroll
        for (int r = 0; r < 4; ++r) { k1[m][r] = 0xFFFFFFFFu; k2[m][r] = 0xFFFFFFFFu; }

#define SPBODY(S)                                                             \
    __builtin_amdgcn_s_barrier();                                             \
    asm volatile("" ::: "memory");                                            \
    _Pragma("unroll")                                                         \
    for (int hp = 0; hp < 2; ++hp) {                                          \
        const int p = 2 * (S) + hp;                                           \
        const short* bp = (const short*)Bs + (p & 3) * 4096;                  \
        f4_t acc[4][2];                                                       \
        _Pragma("unroll")                                                     \
        for (int m = 0; m < 4; ++m) {                                         \
            f4_t z = {0.f,0.f,0.f,0.f}; acc[m][0] = z; acc[m][1] = z;         \
        }                                                                     \
        __builtin_amdgcn_s_setprio(1);                                        \
        {                                                                     \
            f16x8 bb[4];                                                      \
            _Pragma("unroll")                                                 \
            for (int k = 0; k < 4; ++k)                                       \
                bb[k] = *(const f16x8*)(bp + k * 512 + l * 8);                \
            _Pragma("unroll")                                                 \
            for (int k = 0; k < 4; ++k)                                       \
                _Pragma("unroll")                                             \
                for (int m = 0; m < 4; ++m)                                   \
                    acc[m][0] = __builtin_amdgcn_mfma_f32_16x16x32_f16(       \
                        aa[m][k], bb[k], acc[m][0], 0, 0, 0);                 \
        }                                                                     \
        {                                                                     \
            f16x8 bb[4];                                                      \
            _Pragma("unroll")                                                 \
            for (int k = 0; k < 4; ++k)                                       \
                bb[k] = *(const f16x8*)(bp + (k + 4) * 512 + l * 8);          \
            _Pragma("unroll")                                                 \
            for (int k = 0; k < 4; ++k)                                       \
                _Pragma("unroll")                                             \
                for (int m = 0; m < 4; ++m)                                   \
                    acc[m][1] = __builtin_amdgcn_mfma_f32_16x16x32_f16(       \
                        aa[m][k + 4], bb[k], acc[m][1], 0, 0, 0);             \
        }                                                                     \
        __builtin_amdgcn_s_setprio(0);                                        \
        const unsigned int code = (unsigned int)(q * 256 + p * 16 + (l & 15));\
        const float e2b = e2s[p * 16 + (l & 15)];                             \
        _Pragma("unroll")                                                     \
        for (int m = 0; m < 4; ++m)                                           \
            _Pragma("unroll")                                                 \
            for (int r = 0; r < 4; ++r) {                                     \
                float v = e2b - (acc[m][0][r] + acc[m][1][r]);                \
                unsigned int u = __builtin_bit_cast(unsigned int, v);         \
                unsigned int key = (u & 0xFFFFFC00u) | code;  /* v>233>0 */   \
                unsigned int mx = k1[m][r] > key ? k1[m][r] : key;            \
                k1[m][r] = k1[m][r] < key ? k1[m][r] : key;                   \
                k2[m][r] = k2[m][r] < mx ? k2[m][r] : mx;                     \
            }                                                                 \
    }                                                                         \
    __builtin_amdgcn_s_barrier();                                             \
    asm volatile("" ::: "memory");

#pragma unroll 1
    for (int s = 0; s < 7; ++s) {               // stage 1 superphase ahead
        STAGE(2 * s + 2); STAGE(2 * s + 3);
        asm volatile("s_waitcnt vmcnt(4)" ::: "memory");
        SPBODY(s)
    }
    {                                           // tail: nothing left to stage
        asm volatile("s_waitcnt vmcnt(0)" ::: "memory");
        SPBODY(7)
    }

    // top-2 reduce across the 16 lanes sharing each row; write candidates
    {
        int q4 = l >> 4;
#pragma unroll
        for (int m = 0; m < 4; ++m)
#pragma unroll
            for (int r = 0; r < 4; ++r) {
                unsigned int a = k1[m][r], b = k2[m][r];
#pragma unroll
                for (int msk = 1; msk < 16; msk <<= 1) {
                    unsigned int oa = __shfl_xor(a, msk);
                    unsigned int ob = __shfl_xor(b, msk);
                    unsigned int hi_ = a > oa ? a : oa;
                    a = a < oa ? a : oa;
                    b = b < ob ? b : ob;
                    b = b < hi_ ? b : hi_;
                }
                if ((l & 15) == 0) {
                    int row = R0 + w * 64 + m * 16 + q4 * 4 + r;
                    int2 o; o.x = (int)(a & 1023u); o.y = (int)(b & 1023u);
                    *(int2*)(cand + (size_t)row * 8 + q * 2) = o;
                }
            }
    }
#undef SPBODY
#undef STAGE
}

// ---- exact fp32 recheck of 8 candidates (ref formula + tie-break) + gather --
__global__ __launch_bounds__(256) void vq_decide(const float* __restrict__ x,
    const float* __restrict__ cb, const int* __restrict__ cand,
    const float* __restrict__ x2, const float* __restrict__ e2,
    float* __restrict__ outq, float* __restrict__ outi) {
    const int w = threadIdx.x >> 6, l = threadIdx.x & 63;
    const int row = blockIdx.x * 4 + w;
    const int o = l >> 3, j = l & 7;
    const int c = cand[(size_t)row * 8 + o];
    const float4* xr = (const float4*)(x + (size_t)row * D);
    const float4* er = (const float4*)(cb + (size_t)c * D);
    float xe = 0.f;
#pragma unroll
    for (int i = 0; i < 8; ++i) {
        float4 xv = xr[i * 8 + j], ev = er[i * 8 + j];
        xe = fmaf(xv.x, ev.x, xe); xe = fmaf(xv.y, ev.y, xe);
        xe = fmaf(xv.z, ev.z, xe); xe = fmaf(xv.w, ev.w, xe);
    }
    xe += __shfl_xor(xe, 1); xe += __shfl_xor(xe, 2); xe += __shfl_xor(xe, 4);
    float s0 = x2[row] + e2[c];                 // ref order: (x2 + e2) first
    float dist = s0 - 2.f * xe;                 // then - 2*xe
    float best = 3.4e38f; int bi = 0x7fffffff;
#pragma unroll
    for (int oq = 0; oq < 8; ++oq) {
        float dd = __shfl(dist, oq * 8);
        int   ii = __shfl(c,    oq * 8);
        if (dd < best || (dd == best && ii < bi)) { best = dd; bi = ii; }
    }
    float4 v = ((const float4*)(cb + (size_t)bi * D))[l];
    ((float4*)(outq + (size_t)row * D))[l] = v;
    if (l == 0) outi[row] = (float)bi;
}

extern "C" void kernel_launch(void* const* d_in, const int* in_sizes, int n_in,
                              void* d_out, int out_size, void* d_ws, size_t ws_size,
                              hipStream_t stream) {
    const float* x  = (const float*)d_in[0];
    const float* cb = (const float*)d_in[1];
    const int N  = in_sizes[0] / D;   // 32768
    const int Kc = in_sizes[1] / D;   // 1024

    float* outq = (float*)d_out;
    float* outi = outq + (size_t)N * D;

    const size_t needX = (size_t)N * D * 2;                        // 16 MB
    const size_t needS = (size_t)Kc * D * 2 + (size_t)Kc * 4
                       + (size_t)N * 4 + (size_t)N * 8 * 4;        // ~1.7 MB

    short* Xh; char* small;
    if (ws_size >= needX + needS) {
        Xh = (short*)d_ws;
        small = (char*)d_ws + needX;
    } else {
        // Xh lives in d_out[0,16MB). gemm reads it; vq_decide overwrites that
        // region with outq only after gemm completes (stream order). outi is
        // the last 128 KB of d_out -- no overlap.
        Xh = (short*)d_out;
        small = (char*)d_ws;
    }
    short* Eh  = (short*)small;
    float* e2  = (float*)(Eh + (size_t)Kc * D);
    float* x2  = e2 + Kc;
    int*  cand = (int*)(x2 + N);

    conv_all<<<N / 16 + Kc / 16, 256, 0, stream>>>(x, Xh, x2, cb, Eh, e2, N / 16);
    vq_gemm<<<(N / 256) * 4, 256, 0, stream>>>(Xh, Eh, e2, cand);
    vq_decide<<<N / 4, 256, 0, stream>>>(x, cb, cand, x2, e2, outq, outi);
}

// Round 15
// 57.133 us; speedup vs baseline: 1.1384x; 1.0273x over previous
//
#include <hip/hip_runtime.h>

#define D 256

typedef __attribute__((ext_vector_type(8))) _Float16 f16x8;
typedef __attribute__((ext_vector_type(8))) short    s16x8;
typedef __attribute__((ext_vector_type(4))) float    f4_t;

// ---- merged conv: fp32 -> fp16 panel-permute + numpy-pairwise rowsq --------
// blocks [0,nx): x -> xh (NEGATED fp16), x2 ; blocks [nx,..): cb -> eh, e2
// Xh holds fp16(-x) so the gemm MFMA computes e2b - xe directly (seed trick).
__global__ __launch_bounds__(256) void conv_all(
    const float* __restrict__ x, short* __restrict__ xh, float* __restrict__ x2,
    const float* __restrict__ cb, short* __restrict__ eh, float* __restrict__ e2,
    int nx) {
    __shared__ float tile[16 * 264];
    const int t = threadIdx.x;
    const int bid = blockIdx.x;
    const bool isX = bid < nx;
    const float* in; short* out; float* sq; int p;
    if (isX) { in = x;  out = xh; sq = x2; p = bid; }
    else     { in = cb; out = eh; sq = e2; p = bid - nx; }
    const float* src = in + (size_t)p * 16 * 256;
#pragma unroll
    for (int it = 0; it < 4; ++it) {
        int idx = it * 256 + t;
        int row = idx >> 6, c4 = idx & 63;
        float4 v = *(const float4*)(src + row * 256 + c4 * 4);
        *(float4*)(tile + row * 264 + c4 * 4) = v;
    }
    __syncthreads();
    {   // rowsq: 16 threads/row, numpy pairwise order
        int row = t >> 4, lane = t & 15;
        int b = lane >> 3, j = lane & 7;
        const float* q = tile + row * 264 + b * 128 + j;
        float r = 0.f;
        {
#pragma clang fp contract(off)
            for (int i = 0; i < 16; ++i) { float v = q[8 * i]; float s2 = v * v; r = r + s2; }
        }
        r += __shfl_xor(r, 1); r += __shfl_xor(r, 2);
        r += __shfl_xor(r, 4); r += __shfl_xor(r, 8);
        if (lane == 0) sq[p * 16 + row] = r;
    }
    const float sgn = isX ? -1.0f : 1.0f;       // negate x only (exact signflip)
#pragma unroll
    for (int jj = 0; jj < 2; ++jj) {
        int sl = jj * 256 + t;
        int s = sl >> 6, chunk = (sl >> 4) & 3, rr = sl & 15;
        const float* q = tile + rr * 264 + s * 32 + chunk * 8;
        s16x8 h8;
#pragma unroll
        for (int e = 0; e < 8; ++e) {
            _Float16 hv = (_Float16)(sgn * q[e]);
            h8[e] = (short)__builtin_bit_cast(unsigned short, hv);
        }
        *(s16x8*)(out + (size_t)p * 4096 + (size_t)sl * 8) = h8;
    }
}

// ---- main: 256 rows x 256 codes (quarter); 64 rows/wave; R11 sync skeleton --
// A = fp16(-x) in registers; acc0 seeded with e2b (=0.5*e2+256) so the MFMA
// chain itself computes v = e2b - xe: fold is add + and_or + min/med3 (~4 ops
// /element, was 7 -> fold VALU ~12us -> ~7us). Sync/stage ledger identical to
// R11/R14 (validated): iteration s: STAGE(2s+2),(2s+3); vmcnt(4); [barrier;
// read panels 2s,2s+1; MFMA; fold; barrier]. WAR: STAGE(2s+2) writes buf
// (2s-2)&3, read in superphase s-1, completed before s-1's END barrier.
__global__ __launch_bounds__(256, 2) void vq_gemm(
    const short* __restrict__ Xh, const short* __restrict__ Eh,
    const float* __restrict__ e2, int* __restrict__ cand) {
    __shared__ short Bs[4 * 4096];              // 4 panel bufs x 8KB = 32KB
    __shared__ float e2s[256];
    const int tid = threadIdx.x;
    const int l = tid & 63;
    const int w = tid >> 6;
    const int rb = blockIdx.x & 127;            // 128 row-blocks of 256 rows
    const int q  = blockIdx.x >> 7;             // code quarter
    const int R0 = rb * 256;
    const int pcBase = q * 16;

#define STAGE(pp) do {                                                        \
    const short* g_ = Eh + (size_t)(pcBase + (pp)) * 4096 + w * 512 + l * 8;  \
    short* d_ = (short*)Bs + ((pp) & 3) * 4096 + w * 512;                     \
    __builtin_amdgcn_global_load_lds(                                         \
        (const __attribute__((address_space(1))) void*)g_,                    \
        (__attribute__((address_space(3))) void*)d_, 16, 0, 0);               \
    __builtin_amdgcn_global_load_lds(                                         \
        (const __attribute__((address_space(1))) void*)(g_ + 2048),           \
        (__attribute__((address_space(3))) void*)(d_ + 2048), 16, 0, 0);      \
} while (0)

    // A: wave's 64 rows x 256 k, 32 fragments in registers (loaded once)
    f16x8 aa[4][8];
#pragma unroll
    for (int m = 0; m < 4; ++m)
#pragma unroll
        for (int s = 0; s < 8; ++s)
            aa[m][s] = *(const f16x8*)(Xh +
                (size_t)((R0 >> 4) + w * 4 + m) * 4096 + s * 512 + l * 8);

    e2s[tid] = 0.5f * e2[q * 256 + tid] + 256.0f;

    STAGE(0); STAGE(1);                         // panels 0,1
    __syncthreads();                            // full drain + e2s visibility

    unsigned int k1[4][4], k2[4][4];
#pragma unroll
    for (int m = 0; m < 4; ++m)
#pragma unroll
        for (int r = 0; r < 4; ++r) { k1[m][r] = 0xFFFFFFFFu; k2[m][r] = 0xFFFFFFFFu; }

#define SPBODY(S)                                                             \
    __builtin_amdgcn_s_barrier();                                             \
    asm volatile("" ::: "memory");                                            \
    _Pragma("unroll")                                                         \
    for (int hp = 0; hp < 2; ++hp) {                                          \
        const int p = 2 * (S) + hp;                                           \
        const short* bp = (const short*)Bs + (p & 3) * 4096;                  \
        const float e2b = e2s[p * 16 + (l & 15)];                             \
        f4_t acc[4][2];                                                       \
        _Pragma("unroll")                                                     \
        for (int m = 0; m < 4; ++m) {                                         \
            f4_t sd = {e2b, e2b, e2b, e2b};                                   \
            f4_t z  = {0.f, 0.f, 0.f, 0.f};                                   \
            acc[m][0] = sd; acc[m][1] = z;                                    \
        }                                                                     \
        __builtin_amdgcn_s_setprio(1);                                        \
        {                                                                     \
            f16x8 bb[4];                                                      \
            _Pragma("unroll")                                                 \
            for (int k = 0; k < 4; ++k)                                       \
                bb[k] = *(const f16x8*)(bp + k * 512 + l * 8);                \
            _Pragma("unroll")                                                 \
            for (int k = 0; k < 4; ++k)                                       \
                _Pragma("unroll")                                             \
                for (int m = 0; m < 4; ++m)                                   \
                    acc[m][0] = __builtin_amdgcn_mfma_f32_16x16x32_f16(       \
                        aa[m][k], bb[k], acc[m][0], 0, 0, 0);                 \
        }                                                                     \
        {                                                                     \
            f16x8 bb[4];                                                      \
            _Pragma("unroll")                                                 \
            for (int k = 0; k < 4; ++k)                                       \
                bb[k] = *(const f16x8*)(bp + (k + 4) * 512 + l * 8);          \
            _Pragma("unroll")                                                 \
            for (int k = 0; k < 4; ++k)                                       \
                _Pragma("unroll")                                             \
                for (int m = 0; m < 4; ++m)                                   \
                    acc[m][1] = __builtin_amdgcn_mfma_f32_16x16x32_f16(       \
                        aa[m][k + 4], bb[k], acc[m][1], 0, 0, 0);             \
        }                                                                     \
        __builtin_amdgcn_s_setprio(0);                                        \
        const unsigned int code = (unsigned int)(q * 256 + p * 16 + (l & 15));\
        _Pragma("unroll")                                                     \
        for (int m = 0; m < 4; ++m)                                           \
            _Pragma("unroll")                                                 \
            for (int r = 0; r < 4; ++r) {                                     \
                float v = acc[m][0][r] + acc[m][1][r];  /* = e2b - xe > 0 */  \
                unsigned int u = __builtin_bit_cast(unsigned int, v);         \
                unsigned int key = (u & 0xFFFFFC00u) | code;  /* v_and_or */  \
                unsigned int t_ = key > k1[m][r] ? key : k1[m][r];            \
                k2[m][r] = k2[m][r] < t_ ? k2[m][r] : t_;     /* med3 */      \
                k1[m][r] = k1[m][r] < key ? k1[m][r] : key;                   \
            }                                                                 \
    }                                                                         \
    __builtin_amdgcn_s_barrier();                                             \
    asm volatile("" ::: "memory");

#pragma unroll 1
    for (int s = 0; s < 7; ++s) {               // stage 1 superphase ahead
        STAGE(2 * s + 2); STAGE(2 * s + 3);
        asm volatile("s_waitcnt vmcnt(4)" ::: "memory");
        SPBODY(s)
    }
    {                                           // tail: nothing left to stage
        asm volatile("s_waitcnt vmcnt(0)" ::: "memory");
        SPBODY(7)
    }

    // top-2 reduce across the 16 lanes sharing each row; write candidates
    {
        int q4 = l >> 4;
#pragma unroll
        for (int m = 0; m < 4; ++m)
#pragma unroll
            for (int r = 0; r < 4; ++r) {
                unsigned int a = k1[m][r], b = k2[m][r];
#pragma unroll
                for (int msk = 1; msk < 16; msk <<= 1) {
                    unsigned int oa = __shfl_xor(a, msk);
                    unsigned int ob = __shfl_xor(b, msk);
                    unsigned int hi_ = a > oa ? a : oa;
                    a = a < oa ? a : oa;
                    b = b < ob ? b : ob;
                    b = b < hi_ ? b : hi_;
                }
                if ((l & 15) == 0) {
                    int row = R0 + w * 64 + m * 16 + q4 * 4 + r;
                    int2 o; o.x = (int)(a & 1023u); o.y = (int)(b & 1023u);
                    *(int2*)(cand + (size_t)row * 8 + q * 2) = o;
                }
            }
    }
#undef SPBODY
#undef STAGE
}

// ---- exact fp32 recheck of 8 candidates (ref formula + tie-break) + gather --
__global__ __launch_bounds__(256) void vq_decide(const float* __restrict__ x,
    const float* __restrict__ cb, const int* __restrict__ cand,
    const float* __restrict__ x2, const float* __restrict__ e2,
    float* __restrict__ outq, float* __restrict__ outi) {
    const int w = threadIdx.x >> 6, l = threadIdx.x & 63;
    const int row = blockIdx.x * 4 + w;
    const int o = l >> 3, j = l & 7;
    const int c = cand[(size_t)row * 8 + o];
    const float4* xr = (const float4*)(x + (size_t)row * D);
    const float4* er = (const float4*)(cb + (size_t)c * D);
    float xe = 0.f;
#pragma unroll
    for (int i = 0; i < 8; ++i) {
        float4 xv = xr[i * 8 + j], ev = er[i * 8 + j];
        xe = fmaf(xv.x, ev.x, xe); xe = fmaf(xv.y, ev.y, xe);
        xe = fmaf(xv.z, ev.z, xe); xe = fmaf(xv.w, ev.w, xe);
    }
    xe += __shfl_xor(xe, 1); xe += __shfl_xor(xe, 2); xe += __shfl_xor(xe, 4);
    float s0 = x2[row] + e2[c];                 // ref order: (x2 + e2) first
    float dist = s0 - 2.f * xe;                 // then - 2*xe
    float best = 3.4e38f; int bi = 0x7fffffff;
#pragma unroll
    for (int oq = 0; oq < 8; ++oq) {
        float dd = __shfl(dist, oq * 8);
        int   ii = __shfl(c,    oq * 8);
        if (dd < best || (dd == best && ii < bi)) { best = dd; bi = ii; }
    }
    float4 v = ((const float4*)(cb + (size_t)bi * D))[l];
    ((float4*)(outq + (size_t)row * D))[l] = v;
    if (l == 0) outi[row] = (float)bi;
}

extern "C" void kernel_launch(void* const* d_in, const int* in_sizes, int n_in,
                              void* d_out, int out_size, void* d_ws, size_t ws_size,
                              hipStream_t stream) {
    const float* x  = (const float*)d_in[0];
    const float* cb = (const float*)d_in[1];
    const int N  = in_sizes[0] / D;   // 32768
    const int Kc = in_sizes[1] / D;   // 1024

    float* outq = (float*)d_out;
    float* outi = outq + (size_t)N * D;

    const size_t needX = (size_t)N * D * 2;                        // 16 MB
    const size_t needS = (size_t)Kc * D * 2 + (size_t)Kc * 4
                       + (size_t)N * 4 + (size_t)N * 8 * 4;        // ~1.7 MB

    short* Xh; char* small;
    if (ws_size >= needX + needS) {
        Xh = (short*)d_ws;
        small = (char*)d_ws + needX;
    } else {
        // Xh lives in d_out[0,16MB). gemm reads it; vq_decide overwrites that
        // region with outq only after gemm completes (stream order). outi is
        // the last 128 KB of d_out -- no overlap.
        Xh = (short*)d_out;
        small = (char*)d_ws;
    }
    short* Eh  = (short*)small;
    float* e2  = (float*)(Eh + (size_t)Kc * D);
    float* x2  = e2 + Kc;
    int*  cand = (int*)(x2 + N);

    conv_all<<<N / 16 + Kc / 16, 256, 0, stream>>>(x, Xh, x2, cb, Eh, e2, N / 16);
    vq_gemm<<<(N / 256) * 4, 256, 0, stream>>>(Xh, Eh, e2, cand);
    vq_decide<<<N / 4, 256, 0, stream>>>(x, cb, cand, x2, e2, outq, outi);
}